// Round 21
// baseline (396.223 us; speedup 1.0000x reference)
//
#include <hip/hip_runtime.h>
#include <stdint.h>

typedef unsigned short u16;
typedef __attribute__((ext_vector_type(8))) __bf16 bf16x8;
typedef __attribute__((ext_vector_type(4))) __bf16 bf16x4;
typedef __attribute__((ext_vector_type(4))) float f32x4;
typedef __attribute__((ext_vector_type(8))) u16 u16x8;
typedef __attribute__((ext_vector_type(4))) short s16x4;
typedef __attribute__((ext_vector_type(2))) unsigned int u32x2;

#define B_SZ 2
#define T_SZ 2048
#define C_SZ 2048
#define H_SZ 16
#define D_SZ 128
#define NQKV 2304   // C + D + D (q | k | v)
#define ATT_SCALE 0.08838834764831845f
#define LOG2E_SCALE 0.12751744f     // ATT_SCALE * log2(e)
#define DEFER_THR2 11.5415603f      // 8 * log2(e): defer threshold in log2 domain

typedef __attribute__((address_space(1))) void* as1_void_p;
typedef __attribute__((address_space(3))) void* as3_void_p;

__device__ __forceinline__ u16 f2b(float f) {
  union { float f; uint32_t u; } c; c.f = f;
  return (u16)((c.u + 0x7FFFu + ((c.u >> 16) & 1u)) >> 16);
}

__device__ __forceinline__ void gload_lds16(const u16* g, u16* l) {
  __builtin_amdgcn_global_load_lds((as1_void_p)g, (as3_void_p)l, 16, 0, 0);
}

// K=16 bf16 MFMA (intrinsic: hazard recognizer must see it; round-6 verified)
__device__ __forceinline__ f32x4 mfma16(s16x4 a, s16x4 b, f32x4 c) {
#if __has_builtin(__builtin_amdgcn_mfma_f32_16x16x16bf16_1k)
  return __builtin_amdgcn_mfma_f32_16x16x16bf16_1k(a, b, c, 0, 0, 0);
#elif __has_builtin(__builtin_amdgcn_mfma_f32_16x16x16_bf16)
  return __builtin_amdgcn_mfma_f32_16x16x16_bf16(
      __builtin_bit_cast(bf16x4, a), __builtin_bit_cast(bf16x4, b), c, 0, 0, 0);
#else
  u32x2 ua = __builtin_bit_cast(u32x2, a);
  u32x2 ub = __builtin_bit_cast(u32x2, b);
  asm("s_nop 1\n\tv_mfma_f32_16x16x16_bf16 %0, %1, %2, %0\n\ts_nop 7"
      : "+v"(c) : "v"(ua), "v"(ub));
  return c;
#endif
}

// ---------------- merged prep: all casts + bias concat, ONE launch ----------------
__device__ __forceinline__ void cast4(const float* __restrict__ in,
                                      u16* __restrict__ out, int lb, int tid) {
  int idx = lb * 1024 + tid * 4;
  float4 f = *(const float4*)&in[idx];
  ushort4 o4;
  o4.x = f2b(f.x); o4.y = f2b(f.y); o4.z = f2b(f.z); o4.w = f2b(f.w);
  *(ushort4*)&out[idx] = o4;
}

__global__ __launch_bounds__(256) void prep(const float* __restrict__ x,
                                            const float* __restrict__ Wq,
                                            const float* __restrict__ Wk,
                                            const float* __restrict__ Wv,
                                            const float* __restrict__ Wo,
                                            const float* __restrict__ bq,
                                            const float* __restrict__ bk,
                                            const float* __restrict__ bv,
                                            u16* __restrict__ xb,
                                            u16* __restrict__ wqkv,
                                            u16* __restrict__ wob,
                                            float* __restrict__ bqkv) {
  const int bid = blockIdx.x, tid = threadIdx.x;
  if (bid < 8192)       cast4(x,  xb,              bid,         tid);   // 8388608
  else if (bid < 12288) cast4(Wq, wqkv,            bid - 8192,  tid);   // 4194304
  else if (bid < 12544) cast4(Wk, wqkv + 4194304,  bid - 12288, tid);   // 262144
  else if (bid < 12800) cast4(Wv, wqkv + 4456448,  bid - 12544, tid);   // 262144
  else if (bid < 16896) cast4(Wo, wob,             bid - 12800, tid);   // 4194304
  else {
    int e = (bid - 16896) * 1024 + tid * 4;
#pragma unroll
    for (int j = 0; j < 4; j++) {
      int i = e + j;
      if (i < NQKV)
        bqkv[i] = i < C_SZ ? bq[i] : (i < C_SZ + D_SZ ? bk[i - C_SZ] : bv[i - C_SZ - D_SZ]);
    }
  }
}

// ---------------- GEMM: C[M,N] = A[M,K] @ Bm[N,K]^T + bias ----------------
// 128xBN tile, BK=32, 4 waves (2x2), 2-phase pipeline + bijective XCD swizzle.
// BN=96 for the QKV GEMM (768 wg = 3.0/CU); BN=128 for the output GEMM.
template <typename OutT, int BN>
__global__ __launch_bounds__(256) void gemm_bt(const u16* __restrict__ A,
                                               const u16* __restrict__ Bm,
                                               const float* __restrict__ bias,
                                               OutT* __restrict__ C,
                                               int K, int ldc) {
  constexpr int WN = BN / 2;    // per-wave n extent
  constexpr int NF = BN / 32;   // 16-wide n frags per wave
  __shared__ u16 lsA[2][128 * 32];
  __shared__ u16 lsB[2][BN * 32];
  const int tid = threadIdx.x;
  const int lane = tid & 63;
  const int wave = tid >> 6;
  const int wr = wave >> 1, wc = wave & 1;
  const int l16 = lane & 15, lq = lane >> 4;
  const int nwg = gridDim.x * gridDim.y;
  int wg = blockIdx.y * gridDim.x + blockIdx.x;
  wg = (wg & 7) * (nwg >> 3) + (wg >> 3);          // bijective (nwg % 8 == 0)
  const int brow = (wg / gridDim.x) * 128;
  const int bcol = (wg % gridDim.x) * BN;

  f32x4 acc[4][NF] = {};

  auto STAGE = [&](int k0, int bs) {
#pragma unroll
    for (int i = 0; i < 2; i++) {            // A: 512 chunks
      const int cA = i * 256 + wave * 64 + lane;
      const int r = cA >> 2, cc = cA & 3;
      gload_lds16(A + (size_t)(brow + r) * K + k0 + cc * 8,
                  &lsA[bs][(i * 256 + wave * 64) * 8]);
    }
    constexpr int NCB = BN * 4;              // B chunks (512 or 384)
#pragma unroll
    for (int i = 0; i < NCB / 256; i++) {
      const int cB = i * 256 + wave * 64 + lane;
      const int r = cB >> 2, cc = cB & 3;
      gload_lds16(Bm + (size_t)(bcol + r) * K + k0 + cc * 8,
                  &lsB[bs][(i * 256 + wave * 64) * 8]);
    }
    if constexpr (NCB % 256 != 0) {          // remainder: wave-uniform subset
      if (wave < (NCB % 256) / 64) {
        const int cB = (NCB / 256) * 256 + wave * 64 + lane;
        const int r = cB >> 2, cc = cB & 3;
        gload_lds16(Bm + (size_t)(bcol + r) * K + k0 + cc * 8,
                    &lsB[bs][((NCB / 256) * 256 + wave * 64) * 8]);
      }
    }
  };

  STAGE(0, 0);
  __syncthreads();
  int cur = 0;
  for (int k0 = 0; k0 < K; k0 += 32) {
    if (k0 + 32 < K) STAGE(k0 + 32, cur ^ 1);

    bf16x8 af[4], bfr[NF];
#pragma unroll
    for (int mi = 0; mi < 4; mi++)
      af[mi] = *(const bf16x8*)&lsA[cur][(wr * 64 + mi * 16 + l16) * 32 + lq * 8];
#pragma unroll
    for (int ni = 0; ni < NF; ni++)
      bfr[ni] = *(const bf16x8*)&lsB[cur][(wc * WN + ni * 16 + l16) * 32 + lq * 8];
#pragma unroll
    for (int mi = 0; mi < 4; mi++)
#pragma unroll
      for (int ni = 0; ni < NF; ni++)
        acc[mi][ni] = __builtin_amdgcn_mfma_f32_16x16x32_bf16(af[mi], bfr[ni], acc[mi][ni], 0, 0, 0);

    __syncthreads();
    cur ^= 1;
  }

#pragma unroll
  for (int mi = 0; mi < 4; mi++)
#pragma unroll
    for (int ni = 0; ni < NF; ni++) {
      const int col = bcol + wc * WN + ni * 16 + l16;
      const float bb = bias ? bias[col] : 0.0f;
#pragma unroll
      for (int r = 0; r < 4; r++) {
        const int row = brow + wr * 64 + mi * 16 + lq * 4 + r;
        const float v = acc[mi][ni][r] + bb;
        if constexpr (sizeof(OutT) == 2) {
          ((u16*)C)[(size_t)row * ldc + col] = f2b(v);
        } else {
          ((float*)C)[(size_t)row * ldc + col] = v;
        }
      }
    }
}

// ---------------- transpose V: vT[b][d][t] = qkv[b*T+t][2176+d] ----------------
__global__ __launch_bounds__(256) void transpose_v(const u16* __restrict__ qkv,
                                                   u16* __restrict__ vT) {
  __shared__ u16 tile[64 * 136];
  const int tid = threadIdx.x;
  const int t0 = blockIdx.x * 64;
  const int b = blockIdx.y;
#pragma unroll
  for (int i = 0; i < 4; i++) {
    int idx = (i * 256 + tid) * 8;
    int r = idx >> 7, c = idx & 127;
    u16x8 v = *(const u16x8*)&qkv[(size_t)(b * T_SZ + t0 + r) * NQKV + (C_SZ + D_SZ) + c];
    *(u16x8*)&tile[r * 136 + c] = v;
  }
  __syncthreads();
#pragma unroll
  for (int i = 0; i < 4; i++) {
    int idx = (i * 256 + tid) * 8;
    int d = idx >> 6, t = idx & 63;
    u16x8 v;
#pragma unroll
    for (int j = 0; j < 8; j++) v[j] = tile[(t + j) * 136 + d];
    *(u16x8*)&vT[(size_t)(b * D_SZ + d) * T_SZ + t0 + t] = v;
  }
}

// ---------------- per-wave QK^T (swapped operands) ----------------
// lk: [64 kv][128 d] bf16, 16B chunks XOR-swizzled by (row&7)
__device__ __forceinline__ void qk_part(const u16* lk, const bf16x8 (&aq)[4],
                                        f32x4 (&s)[4], int l16, int lq) {
#pragma unroll
  for (int kk = 0; kk < 4; kk++) {
#pragma unroll
    for (int nb = 0; nb < 4; nb++) {
      const int row = nb * 16 + l16;
      const bf16x8 kf = *(const bf16x8*)&lk[row * 128 + (((kk * 4 + lq) ^ (row & 7)) << 3)];
      s[nb] = __builtin_amdgcn_mfma_f32_16x16x32_bf16(kf, aq[kk], s[nb], 0, 0, 0);
    }
  }
}

// ---------------- per-wave softmax + PV ----------------
// Q is PRE-SCALED by ATT_SCALE*log2(e) at block init: p = exp2(s - m) directly.
// S^T regs: lane has q=l16 fixed, kv = nb*16+lq*4+rr. PV K=16 MFMA B-operand
// (col=l16, k=lq*4+e) == the S^T fragment -> zero cross-lane P movement.
// V read DIRECT from global (m169: V-staging of L2-fit data is pure overhead;
// the 8B LDS reads were the dominant bank-conflict source, 13M cyc/dispatch).
// The 16KB V tile is reused by all 8 waves -> L1/L2 hits after first touch.
template <bool DIAG>
__device__ __forceinline__ void sm_pv(const u16* __restrict__ gv, int kv0,
                                      f32x4 (&s)[4], f32x4 (&o)[8],
                                      float& lp, float& m, int q_rel, int l16, int lq) {
  if (DIAG) {
#pragma unroll
    for (int nb = 0; nb < 4; nb++)
#pragma unroll
      for (int rr = 0; rr < 4; rr++)
        if (nb * 16 + lq * 4 + rr > q_rel) s[nb][rr] -= 1e9f;  // additive causal mask
  }
  // balanced lane-local max tree (no cross-lane ops on the common path)
  float m0 = fmaxf(fmaxf(s[0][0], s[0][1]), fmaxf(s[0][2], s[0][3]));
  float m1 = fmaxf(fmaxf(s[1][0], s[1][1]), fmaxf(s[1][2], s[1][3]));
  float m2 = fmaxf(fmaxf(s[2][0], s[2][1]), fmaxf(s[2][2], s[2][3]));
  float m3 = fmaxf(fmaxf(s[3][0], s[3][1]), fmaxf(s[3][2], s[3][3]));
  float mx = fmaxf(fmaxf(m0, m1), fmaxf(m2, m3));
  if (__any(mx > m + DEFER_THR2)) {  // defer-max (T13); fires iff row-max fires
    float rmx = fmaxf(mx, __shfl_xor(mx, 16, 64));   // row max (rare path)
    rmx = fmaxf(rmx, __shfl_xor(rmx, 32, 64));
    const float mnew = fmaxf(m, rmx);                // row-uniform
    const float alpha = exp2f(m - mnew);
    m = mnew;
    lp *= alpha;
#pragma unroll
    for (int nd = 0; nd < 8; nd++)
#pragma unroll
      for (int e = 0; e < 4; e++) o[nd][e] *= alpha;
  }
#pragma unroll
  for (int nb = 0; nb < 4; nb++) {
    bf16x4 pbv;
#pragma unroll
    for (int e = 0; e < 4; e++) {
      const float p = exp2f(s[nb][e] - m);
      lp += p;
      pbv[e] = (__bf16)p;          // native cvt (compiler may pack pairs)
    }
    const s16x4 pb = __builtin_bit_cast(s16x4, pbv);
    const int co = kv0 + (((nb << 1) | (lq >> 1)) << 3) + ((lq & 1) << 2);
    __builtin_amdgcn_s_setprio(1);   // T5
#pragma unroll
    for (int nd = 0; nd < 8; nd++) {
      const int row = nd * 16 + l16;
      const s16x4 av = *(const s16x4*)&gv[(size_t)row * T_SZ + co];
      o[nd] = mfma16(av, pb, o[nd]);
    }
    __builtin_amdgcn_s_setprio(0);
  }
}

// ---------------- flash attention, causal, MQA ----------------
// grid (16, H, B), 512 threads = 8 waves, ALL on ONE 128-row q-tile
// (wave wv owns rows qt*128 + wv*16). nkt = 2*qt+2; b-complementary qt mapping
// keeps co-resident nkt sums constant. K double-buffered in LDS (32KB); V read
// direct from global (m169). One vmcnt-light barrier per iteration.
__global__ __launch_bounds__(512, 4) void attn_fwd(const u16* __restrict__ qkv,
                                                   const u16* __restrict__ vT,
                                                   u16* __restrict__ out) {
  __shared__ u16 lsK[2][64 * 128];
  const int tid = threadIdx.x;
  const int wv = tid >> 6, lane = tid & 63;
  const int l16 = lane & 15, lq = lane >> 4;
  const int h = blockIdx.y;
  const int b = blockIdx.z;
  // 128-row q-tile index in [0,16); heavy-first for b=0, complementary for b=1
  const int qt = (b == 0) ? (15 - blockIdx.x) : blockIdx.x;
  const int bT = b * T_SZ;
  const int wq0 = qt * 128 + wv * 16;    // this wave's first q row

  bf16x8 aq[4];
  {
    const size_t qrow = (size_t)(bT + wq0 + l16) * NQKV + h * D_SZ;
#pragma unroll
    for (int kk = 0; kk < 4; kk++) {
      aq[kk] = *(const bf16x8*)&qkv[qrow + kk * 32 + lq * 8];
      // pre-scale Q by ATT_SCALE*log2(e): softmax then needs no per-value mul
#pragma unroll
      for (int e = 0; e < 8; e++)
        aq[kk][e] = (__bf16)((float)aq[kk][e] * LOG2E_SCALE);
    }
  }

  f32x4 o[8] = {};
  float lp = 0.f, m = -INFINITY;

  // K staging pointers: 512 threads, 2 x 16B loads each.
  // linear dest = idx*16B (idx = i*512 + tid); source pre-swizzled by row.
  const u16 *kp0, *kp1;
  {
    const int kr0 = tid >> 4,         kc0 = tid & 15;
    const int kr1 = (512 + tid) >> 4, kc1 = tid & 15;
    kp0 = qkv + (size_t)(bT + kr0) * NQKV + C_SZ + (size_t)((kc0 ^ (kr0 & 7)) * 8);
    kp1 = qkv + (size_t)(bT + kr1) * NQKV + C_SZ + (size_t)((kc1 ^ (kr1 & 7)) * 8);
  }
  const int kd0 = wv * 512, kd1 = (8 + wv) * 512;
  const u16* gv = vT + (size_t)b * D_SZ * T_SZ;   // V base (direct-global reads)

  auto STAGE_K = [&](int kt, int bf) {
    const size_t off = (size_t)kt * (64 * NQKV);
    gload_lds16(kp0 + off, &lsK[bf][kd0]);
    gload_lds16(kp1 + off, &lsK[bf][kd1]);
  };

  const int nkt = 2 * qt + 2;
  STAGE_K(0, 0);
  __syncthreads();   // prologue: drain before first consume
  int cur = 0;
  for (int kt = 0; kt < nkt; kt++) {
    if (kt + 1 < nkt) STAGE_K(kt + 1, cur ^ 1);   // flies under the iteration
    const int kv0 = kt << 6;
    if (kv0 <= wq0 + 15) {              // this wave still has unmasked work
      f32x4 s[4] = {};
      __builtin_amdgcn_s_setprio(1);    // T5: favor QK MFMA cluster
      qk_part(lsK[cur], aq, s, l16, lq);
      __builtin_amdgcn_s_setprio(0);
      if (kv0 + 63 <= wq0)
        sm_pv<false>(gv, kv0, s, o, lp, m, 0, l16, lq);
      else
        sm_pv<true>(gv, kv0, s, o, lp, m, wq0 + l16 - kv0, l16, lq);
    }
    // single sync point: drain K prefetch (2 loads, issued a full iteration
    // ago -> covered), publish LDS writes, protect [cur] from next staging.
    asm volatile("s_waitcnt vmcnt(0)" ::: "memory");
    __builtin_amdgcn_sched_barrier(0);
    __builtin_amdgcn_s_barrier();
    cur ^= 1;
  }

  // epilogue: reduce deferred row sum, normalize, store (O^T: 8B contiguous)
  lp += __shfl_xor(lp, 16, 64);
  lp += __shfl_xor(lp, 32, 64);
  const float r = __builtin_amdgcn_rcpf(lp);
  const size_t rowb = (size_t)(bT + wq0 + l16) * C_SZ + h * D_SZ;
#pragma unroll
  for (int nd = 0; nd < 8; nd++) {
    ushort4 sv;
    sv.x = f2b(o[nd][0] * r); sv.y = f2b(o[nd][1] * r);
    sv.z = f2b(o[nd][2] * r); sv.w = f2b(o[nd][3] * r);
    *(ushort4*)&out[rowb + nd * 16 + lq * 4] = sv;
  }
}

extern "C" void kernel_launch(void* const* d_in, const int* in_sizes, int n_in,
                              void* d_out, int out_size, void* d_ws, size_t ws_size,
                              hipStream_t stream) {
  const float* x  = (const float*)d_in[0];
  // d_in[1] = attn_mask: causal, hardcoded in attn_fwd
  const float* Wq = (const float*)d_in[2];
  const float* bq = (const float*)d_in[3];
  const float* Wk = (const float*)d_in[4];
  const float* bk = (const float*)d_in[5];
  const float* Wv = (const float*)d_in[6];
  const float* bv = (const float*)d_in[7];
  const float* Wo = (const float*)d_in[8];
  const float* bo = (const float*)d_in[9];
  float* out = (float*)d_out;

  // workspace layout (bytes), all 256-aligned
  char* ws = (char*)d_ws;
  if (ws_size < 71312384) return;  // need ~68 MB
  u16* xb     = (u16*)(ws + 0);          // 4096x2048 bf16
  u16* wqkv   = (u16*)(ws + 16777216);   // 2304x2048 bf16 (Wq|Wk|Wv rows)
  u16* wob    = (u16*)(ws + 26214400);   // 2048x2048 bf16
  u16* qkv    = (u16*)(ws + 34603008);   // 4096x2304 bf16
  u16* vT     = (u16*)(ws + 53477376);   // 2x128x2048 bf16
  u16* ao     = (u16*)(ws + 54525952);   // 4096x2048 bf16
  float* bqkv = (float*)(ws + 71303168); // 2304 f32

  prep<<<16899, 256, 0, stream>>>(x, Wq, Wk, Wv, Wo, bq, bk, bv, xb, wqkv, wob, bqkv);

  // qkv = xb @ wqkv^T + bias   [4096, 2304]  (128x96 tiles: 768 wg = 3.0/CU)
  gemm_bt<u16, 96><<<dim3(24, 32), 256, 0, stream>>>(xb, wqkv, bqkv, qkv, 2048, NQKV);
  transpose_v<<<dim3(32, 2), 256, 0, stream>>>(qkv, vT);
  attn_fwd<<<dim3(16, 16, 2), 512, 0, stream>>>(qkv, vT, ao);
  // out = ao @ wob^T + bo      [4096, 2048] fp32  (128x128: 512 wg = 2.0/CU)
  gemm_bt<float, 128><<<dim3(16, 32), 256, 0, stream>>>(ao, wob, bo, out, 2048, 2048);
}

// Round 22
// 201.581 us; speedup vs baseline: 1.9656x; 1.9656x over previous
//
#include <hip/hip_runtime.h>
#include <stdint.h>

typedef unsigned short u16;
typedef __attribute__((ext_vector_type(8))) __bf16 bf16x8;
typedef __attribute__((ext_vector_type(4))) __bf16 bf16x4;
typedef __attribute__((ext_vector_type(4))) float f32x4;
typedef __attribute__((ext_vector_type(8))) u16 u16x8;
typedef __attribute__((ext_vector_type(4))) short s16x4;
typedef __attribute__((ext_vector_type(2))) unsigned int u32x2;

#define B_SZ 2
#define T_SZ 2048
#define C_SZ 2048
#define H_SZ 16
#define D_SZ 128
#define NQKV 2304   // C + D + D (q | k | v)
#define ATT_SCALE 0.08838834764831845f
#define LOG2E_SCALE 0.12751744f     // ATT_SCALE * log2(e)
#define DEFER_THR2 11.5415603f      // 8 * log2(e): defer threshold in log2 domain

typedef __attribute__((address_space(1))) void* as1_void_p;
typedef __attribute__((address_space(3))) void* as3_void_p;

__device__ __forceinline__ u16 f2b(float f) {
  union { float f; uint32_t u; } c; c.f = f;
  return (u16)((c.u + 0x7FFFu + ((c.u >> 16) & 1u)) >> 16);
}

__device__ __forceinline__ void gload_lds16(const u16* g, u16* l) {
  __builtin_amdgcn_global_load_lds((as1_void_p)g, (as3_void_p)l, 16, 0, 0);
}

// K=16 bf16 MFMA (intrinsic: hazard recognizer must see it; round-6 verified)
__device__ __forceinline__ f32x4 mfma16(s16x4 a, s16x4 b, f32x4 c) {
#if __has_builtin(__builtin_amdgcn_mfma_f32_16x16x16bf16_1k)
  return __builtin_amdgcn_mfma_f32_16x16x16bf16_1k(a, b, c, 0, 0, 0);
#elif __has_builtin(__builtin_amdgcn_mfma_f32_16x16x16_bf16)
  return __builtin_amdgcn_mfma_f32_16x16x16_bf16(
      __builtin_bit_cast(bf16x4, a), __builtin_bit_cast(bf16x4, b), c, 0, 0, 0);
#else
  u32x2 ua = __builtin_bit_cast(u32x2, a);
  u32x2 ub = __builtin_bit_cast(u32x2, b);
  asm("s_nop 1\n\tv_mfma_f32_16x16x16_bf16 %0, %1, %2, %0\n\ts_nop 7"
      : "+v"(c) : "v"(ua), "v"(ub));
  return c;
#endif
}

// ---------------- merged prep: all casts + bias concat, ONE launch ----------------
__device__ __forceinline__ void cast4(const float* __restrict__ in,
                                      u16* __restrict__ out, int lb, int tid) {
  int idx = lb * 1024 + tid * 4;
  float4 f = *(const float4*)&in[idx];
  ushort4 o4;
  o4.x = f2b(f.x); o4.y = f2b(f.y); o4.z = f2b(f.z); o4.w = f2b(f.w);
  *(ushort4*)&out[idx] = o4;
}

__global__ __launch_bounds__(256) void prep(const float* __restrict__ x,
                                            const float* __restrict__ Wq,
                                            const float* __restrict__ Wk,
                                            const float* __restrict__ Wv,
                                            const float* __restrict__ Wo,
                                            const float* __restrict__ bq,
                                            const float* __restrict__ bk,
                                            const float* __restrict__ bv,
                                            u16* __restrict__ xb,
                                            u16* __restrict__ wqkv,
                                            u16* __restrict__ wob,
                                            float* __restrict__ bqkv) {
  const int bid = blockIdx.x, tid = threadIdx.x;
  if (bid < 8192)       cast4(x,  xb,              bid,         tid);   // 8388608
  else if (bid < 12288) cast4(Wq, wqkv,            bid - 8192,  tid);   // 4194304
  else if (bid < 12544) cast4(Wk, wqkv + 4194304,  bid - 12288, tid);   // 262144
  else if (bid < 12800) cast4(Wv, wqkv + 4456448,  bid - 12544, tid);   // 262144
  else if (bid < 16896) cast4(Wo, wob,             bid - 12800, tid);   // 4194304
  else {
    int e = (bid - 16896) * 1024 + tid * 4;
#pragma unroll
    for (int j = 0; j < 4; j++) {
      int i = e + j;
      if (i < NQKV)
        bqkv[i] = i < C_SZ ? bq[i] : (i < C_SZ + D_SZ ? bk[i - C_SZ] : bv[i - C_SZ - D_SZ]);
    }
  }
}

// ---------------- GEMM: C[M,N] = A[M,K] @ Bm[N,K]^T + bias ----------------
// 128xBN tile, BK=32, 4 waves (2x2), 2-phase pipeline + bijective XCD swizzle.
// BN=96 for the QKV GEMM: N=2304=24x96 -> grid 768 = exactly 3.0 blocks/CU.
// BN=128 for the output GEMM (512 = 2.0/CU exact).
template <typename OutT, int BN>
__global__ __launch_bounds__(256) void gemm_bt(const u16* __restrict__ A,
                                               const u16* __restrict__ Bm,
                                               const float* __restrict__ bias,
                                               OutT* __restrict__ C,
                                               int K, int ldc) {
  constexpr int WN = BN / 2;    // per-wave n extent
  constexpr int NF = BN / 32;   // 16-wide n frags per wave
  __shared__ u16 lsA[2][128 * 32];
  __shared__ u16 lsB[2][BN * 32];
  const int tid = threadIdx.x;
  const int lane = tid & 63;
  const int wave = tid >> 6;
  const int wr = wave >> 1, wc = wave & 1;
  const int l16 = lane & 15, lq = lane >> 4;
  const int nwg = gridDim.x * gridDim.y;
  int wg = blockIdx.y * gridDim.x + blockIdx.x;
  wg = (wg & 7) * (nwg >> 3) + (wg >> 3);          // bijective (nwg % 8 == 0)
  const int brow = (wg / gridDim.x) * 128;
  const int bcol = (wg % gridDim.x) * BN;

  f32x4 acc[4][NF] = {};

  // chunk c (16B, 8 elems): source row = c>>2, col = (c&3)*8; dest linear c*8.
  auto STAGE = [&](int k0, int bs) {
#pragma unroll
    for (int i = 0; i < 2; i++) {            // A: 512 chunks
      const int cA = i * 256 + wave * 64 + lane;
      const int r = cA >> 2, cc = cA & 3;
      gload_lds16(A + (size_t)(brow + r) * K + k0 + cc * 8,
                  &lsA[bs][(i * 256 + wave * 64) * 8]);
    }
    constexpr int NCB = BN * 4;              // B chunks (512 or 384)
#pragma unroll
    for (int i = 0; i < NCB / 256; i++) {
      const int cB = i * 256 + wave * 64 + lane;
      const int r = cB >> 2, cc = cB & 3;
      gload_lds16(Bm + (size_t)(bcol + r) * K + k0 + cc * 8,
                  &lsB[bs][(i * 256 + wave * 64) * 8]);
    }
    if constexpr (NCB % 256 != 0) {          // remainder: wave-uniform subset
      if (wave < (NCB % 256) / 64) {
        const int cB = (NCB / 256) * 256 + wave * 64 + lane;
        const int r = cB >> 2, cc = cB & 3;
        gload_lds16(Bm + (size_t)(bcol + r) * K + k0 + cc * 8,
                    &lsB[bs][((NCB / 256) * 256 + wave * 64) * 8]);
      }
    }
  };

  STAGE(0, 0);
  __syncthreads();
  int cur = 0;
  for (int k0 = 0; k0 < K; k0 += 32) {
    if (k0 + 32 < K) STAGE(k0 + 32, cur ^ 1);

    bf16x8 af[4], bfr[NF];
#pragma unroll
    for (int mi = 0; mi < 4; mi++)
      af[mi] = *(const bf16x8*)&lsA[cur][(wr * 64 + mi * 16 + l16) * 32 + lq * 8];
#pragma unroll
    for (int ni = 0; ni < NF; ni++)
      bfr[ni] = *(const bf16x8*)&lsB[cur][(wc * WN + ni * 16 + l16) * 32 + lq * 8];
#pragma unroll
    for (int mi = 0; mi < 4; mi++)
#pragma unroll
      for (int ni = 0; ni < NF; ni++)
        acc[mi][ni] = __builtin_amdgcn_mfma_f32_16x16x32_bf16(af[mi], bfr[ni], acc[mi][ni], 0, 0, 0);

    __syncthreads();
    cur ^= 1;
  }

#pragma unroll
  for (int mi = 0; mi < 4; mi++)
#pragma unroll
    for (int ni = 0; ni < NF; ni++) {
      const int col = bcol + wc * WN + ni * 16 + l16;
      const float bb = bias ? bias[col] : 0.0f;
#pragma unroll
      for (int r = 0; r < 4; r++) {
        const int row = brow + wr * 64 + mi * 16 + lq * 4 + r;
        const float v = acc[mi][ni][r] + bb;
        if constexpr (sizeof(OutT) == 2) {
          ((u16*)C)[(size_t)row * ldc + col] = f2b(v);
        } else {
          ((float*)C)[(size_t)row * ldc + col] = v;
        }
      }
    }
}

// ---------------- transpose V: vT[b][d][t] = qkv[b*T+t][2176+d] ----------------
__global__ __launch_bounds__(256) void transpose_v(const u16* __restrict__ qkv,
                                                   u16* __restrict__ vT) {
  __shared__ u16 tile[64 * 136];
  const int tid = threadIdx.x;
  const int t0 = blockIdx.x * 64;
  const int b = blockIdx.y;
#pragma unroll
  for (int i = 0; i < 4; i++) {
    int idx = (i * 256 + tid) * 8;
    int r = idx >> 7, c = idx & 127;
    u16x8 v = *(const u16x8*)&qkv[(size_t)(b * T_SZ + t0 + r) * NQKV + (C_SZ + D_SZ) + c];
    *(u16x8*)&tile[r * 136 + c] = v;
  }
  __syncthreads();
#pragma unroll
  for (int i = 0; i < 4; i++) {
    int idx = (i * 256 + tid) * 8;
    int d = idx >> 6, t = idx & 63;
    u16x8 v;
#pragma unroll
    for (int j = 0; j < 8; j++) v[j] = tile[(t + j) * 136 + d];
    *(u16x8*)&vT[(size_t)(b * D_SZ + d) * T_SZ + t0 + t] = v;
  }
}

// ---------------- per-wave QK^T (swapped operands) ----------------
// lk: [64 kv][128 d] bf16, 16B chunks XOR-swizzled by (row&7)
__device__ __forceinline__ void qk_part(const u16* lk, const bf16x8 (&aq)[4],
                                        f32x4 (&s)[4], int l16, int lq) {
#pragma unroll
  for (int kk = 0; kk < 4; kk++) {
#pragma unroll
    for (int nb = 0; nb < 4; nb++) {
      const int row = nb * 16 + l16;
      const bf16x8 kf = *(const bf16x8*)&lk[row * 128 + (((kk * 4 + lq) ^ (row & 7)) << 3)];
      s[nb] = __builtin_amdgcn_mfma_f32_16x16x32_bf16(kf, aq[kk], s[nb], 0, 0, 0);
    }
  }
}

// ---------------- per-wave softmax + PV ----------------
// Q is PRE-SCALED by ATT_SCALE*log2(e) at block init: p = exp2(s - m) directly.
// S^T regs: lane has q=l16 fixed, kv = nb*16+lq*4+rr. PV K=16 MFMA B-operand
// (col=l16, k=lq*4+e) == the S^T fragment -> zero cross-lane P movement.
// lv: [128 d][64 t] bf16, 16B chunks XOR-swizzled by (row&7). NOTE round-21:
// direct-global V reads were 3x SLOWER (scattered per-MFMA gathers on the
// dataflow critical path) -- LDS staging here converts those into one
// coalesced prefetch; keep it.
template <bool DIAG>
__device__ __forceinline__ void sm_pv(const u16* lv, f32x4 (&s)[4], f32x4 (&o)[8],
                                      float& lp, float& m, int q_rel, int l16, int lq) {
  if (DIAG) {
#pragma unroll
    for (int nb = 0; nb < 4; nb++)
#pragma unroll
      for (int rr = 0; rr < 4; rr++)
        if (nb * 16 + lq * 4 + rr > q_rel) s[nb][rr] -= 1e9f;  // additive causal mask
  }
  // balanced lane-local max tree (no cross-lane ops on the common path)
  float m0 = fmaxf(fmaxf(s[0][0], s[0][1]), fmaxf(s[0][2], s[0][3]));
  float m1 = fmaxf(fmaxf(s[1][0], s[1][1]), fmaxf(s[1][2], s[1][3]));
  float m2 = fmaxf(fmaxf(s[2][0], s[2][1]), fmaxf(s[2][2], s[2][3]));
  float m3 = fmaxf(fmaxf(s[3][0], s[3][1]), fmaxf(s[3][2], s[3][3]));
  float mx = fmaxf(fmaxf(m0, m1), fmaxf(m2, m3));
  if (__any(mx > m + DEFER_THR2)) {  // defer-max (T13); fires iff row-max fires
    float rmx = fmaxf(mx, __shfl_xor(mx, 16, 64));   // row max (rare path)
    rmx = fmaxf(rmx, __shfl_xor(rmx, 32, 64));
    const float mnew = fmaxf(m, rmx);                // row-uniform
    const float alpha = exp2f(m - mnew);
    m = mnew;
    lp *= alpha;
#pragma unroll
    for (int nd = 0; nd < 8; nd++)
#pragma unroll
      for (int e = 0; e < 4; e++) o[nd][e] *= alpha;
  }
#pragma unroll
  for (int nb = 0; nb < 4; nb++) {
    bf16x4 pbv;
#pragma unroll
    for (int e = 0; e < 4; e++) {
      const float p = exp2f(s[nb][e] - m);
      lp += p;
      pbv[e] = (__bf16)p;          // native cvt (compiler may pack pairs)
    }
    const s16x4 pb = __builtin_bit_cast(s16x4, pbv);
    __builtin_amdgcn_s_setprio(1);   // T5
#pragma unroll
    for (int nd = 0; nd < 8; nd++) {
      const int row = nd * 16 + l16;
      const s16x4 av = *(const s16x4*)&lv[row * 64 +
          ((((nb << 1) | (lq >> 1)) ^ (row & 7)) << 3) + ((lq & 1) << 2)];
      o[nd] = mfma16(av, pb, o[nd]);
    }
    __builtin_amdgcn_s_setprio(0);
  }
}

// ---------------- flash attention, causal, MQA ----------------
// grid (16, H, B), 512 threads = 8 waves, ALL on ONE 128-row q-tile
// (wave wv owns rows qt*128 + wv*16). nkt = 2*qt+2; b-complementary qt mapping
// keeps co-resident nkt sums constant. K+V double-buffered (64KB, 2 blocks/CU),
// one vmcnt(0)+barrier per iteration (measured plateau ~91.5us across all
// structural/micro variants -- decomposition-bound at 16 waves/CU).
__global__ __launch_bounds__(512, 4) void attn_fwd(const u16* __restrict__ qkv,
                                                   const u16* __restrict__ vT,
                                                   u16* __restrict__ out) {
  __shared__ u16 lsK[2][64 * 128];
  __shared__ u16 lsV[2][128 * 64];
  const int tid = threadIdx.x;
  const int wv = tid >> 6, lane = tid & 63;
  const int l16 = lane & 15, lq = lane >> 4;
  const int h = blockIdx.y;
  const int b = blockIdx.z;
  // 128-row q-tile index in [0,16); heavy-first for b=0, complementary for b=1
  const int qt = (b == 0) ? (15 - blockIdx.x) : blockIdx.x;
  const int bT = b * T_SZ;
  const int wq0 = qt * 128 + wv * 16;    // this wave's first q row

  bf16x8 aq[4];
  {
    const size_t qrow = (size_t)(bT + wq0 + l16) * NQKV + h * D_SZ;
#pragma unroll
    for (int kk = 0; kk < 4; kk++) {
      aq[kk] = *(const bf16x8*)&qkv[qrow + kk * 32 + lq * 8];
      // pre-scale Q by ATT_SCALE*log2(e): softmax then needs no per-value mul
#pragma unroll
      for (int e = 0; e < 8; e++)
        aq[kk][e] = (__bf16)((float)aq[kk][e] * LOG2E_SCALE);
    }
  }

  f32x4 o[8] = {};
  float lp = 0.f, m = -INFINITY;

  // staging pointers: 512 threads, 2 x 16B loads each for K and for V.
  // linear dest = idx*16B (idx = i*512 + tid); source pre-swizzled by row.
  const u16 *kp0, *kp1, *vp0, *vp1;
  {
    const int kr0 = tid >> 4,         kc0 = tid & 15;
    const int kr1 = (512 + tid) >> 4, kc1 = tid & 15;
    kp0 = qkv + (size_t)(bT + kr0) * NQKV + C_SZ + (size_t)((kc0 ^ (kr0 & 7)) * 8);
    kp1 = qkv + (size_t)(bT + kr1) * NQKV + C_SZ + (size_t)((kc1 ^ (kr1 & 7)) * 8);
    const int vr0 = tid >> 3,         vc0 = tid & 7;
    const int vr1 = (512 + tid) >> 3, vc1 = tid & 7;
    vp0 = vT + (size_t)(b * D_SZ + vr0) * T_SZ + (vc0 ^ (vr0 & 7)) * 8;
    vp1 = vT + (size_t)(b * D_SZ + vr1) * T_SZ + (vc1 ^ (vr1 & 7)) * 8;
  }
  const int kd0 = wv * 512, kd1 = (8 + wv) * 512;

  auto STAGE_K = [&](int kt, int bf) {
    const size_t off = (size_t)kt * (64 * NQKV);
    gload_lds16(kp0 + off, &lsK[bf][kd0]);
    gload_lds16(kp1 + off, &lsK[bf][kd1]);
  };
  auto STAGE_V = [&](int kt, int bf) {
    const int off = kt * 64;
    gload_lds16(vp0 + off, &lsV[bf][kd0]);
    gload_lds16(vp1 + off, &lsV[bf][kd1]);
  };

  const int nkt = 2 * qt + 2;
  STAGE_K(0, 0);
  STAGE_V(0, 0);
  __syncthreads();   // prologue: full drain before first consume
  int cur = 0;
  for (int kt = 0; kt < nkt; kt++) {
    if (kt + 1 < nkt) {                 // prefetch both tiles into cur^1;
      STAGE_K(kt + 1, cur ^ 1);         // flies under the WHOLE iteration
      STAGE_V(kt + 1, cur ^ 1);
    }
    const int kv0 = kt << 6;
    if (kv0 <= wq0 + 15) {              // this wave still has unmasked work
      f32x4 s[4] = {};
      __builtin_amdgcn_s_setprio(1);    // T5: favor QK MFMA cluster
      qk_part(lsK[cur], aq, s, l16, lq);
      __builtin_amdgcn_s_setprio(0);
      if (kv0 + 63 <= wq0)
        sm_pv<false>(lsV[cur], s, o, lp, m, 0, l16, lq);
      else
        sm_pv<true>(lsV[cur], s, o, lp, m, wq0 + l16 - kv0, l16, lq);
    }
    // single sync point: drain prefetch (covered by compute above), publish
    // LDS writes, and protect [cur] from next iteration's staging.
    asm volatile("s_waitcnt vmcnt(0)" ::: "memory");
    __builtin_amdgcn_sched_barrier(0);
    __builtin_amdgcn_s_barrier();
    cur ^= 1;
  }

  // epilogue: reduce deferred row sum, normalize, store (O^T: 8B contiguous)
  lp += __shfl_xor(lp, 16, 64);
  lp += __shfl_xor(lp, 32, 64);
  const float r = __builtin_amdgcn_rcpf(lp);
  const size_t rowb = (size_t)(bT + wq0 + l16) * C_SZ + h * D_SZ;
#pragma unroll
  for (int nd = 0; nd < 8; nd++) {
    ushort4 sv;
    sv.x = f2b(o[nd][0] * r); sv.y = f2b(o[nd][1] * r);
    sv.z = f2b(o[nd][2] * r); sv.w = f2b(o[nd][3] * r);
    *(ushort4*)&out[rowb + nd * 16 + lq * 4] = sv;
  }
}

extern "C" void kernel_launch(void* const* d_in, const int* in_sizes, int n_in,
                              void* d_out, int out_size, void* d_ws, size_t ws_size,
                              hipStream_t stream) {
  const float* x  = (const float*)d_in[0];
  // d_in[1] = attn_mask: causal, hardcoded in attn_fwd
  const float* Wq = (const float*)d_in[2];
  const float* bq = (const float*)d_in[3];
  const float* Wk = (const float*)d_in[4];
  const float* bk = (const float*)d_in[5];
  const float* Wv = (const float*)d_in[6];
  const float* bv = (const float*)d_in[7];
  const float* Wo = (const float*)d_in[8];
  const float* bo = (const float*)d_in[9];
  float* out = (float*)d_out;

  // workspace layout (bytes), all 256-aligned
  char* ws = (char*)d_ws;
  if (ws_size < 71312384) return;  // need ~68 MB
  u16* xb     = (u16*)(ws + 0);          // 4096x2048 bf16
  u16* wqkv   = (u16*)(ws + 16777216);   // 2304x2048 bf16 (Wq|Wk|Wv rows)
  u16* wob    = (u16*)(ws + 26214400);   // 2048x2048 bf16
  u16* qkv    = (u16*)(ws + 34603008);   // 4096x2304 bf16
  u16* vT     = (u16*)(ws + 53477376);   // 2x128x2048 bf16
  u16* ao     = (u16*)(ws + 54525952);   // 4096x2048 bf16
  float* bqkv = (float*)(ws + 71303168); // 2304 f32

  prep<<<16899, 256, 0, stream>>>(x, Wq, Wk, Wv, Wo, bq, bk, bv, xb, wqkv, wob, bqkv);

  // qkv = xb @ wqkv^T + bias   [4096, 2304]  (128x96 tiles: 768 wg = 3.0/CU)
  gemm_bt<u16, 96><<<dim3(24, 32), 256, 0, stream>>>(xb, wqkv, bqkv, qkv, 2048, NQKV);
  transpose_v<<<dim3(32, 2), 256, 0, stream>>>(qkv, vT);
  attn_fwd<<<dim3(16, 16, 2), 512, 0, stream>>>(qkv, vT, ao);
  // out = ao @ wob^T + bo      [4096, 2048] fp32  (128x128: 512 wg = 2.0/CU)
  gemm_bt<float, 128><<<dim3(16, 32), 256, 0, stream>>>(ao, wob, bo, out, 2048, 2048);
}

// Round 23
// 199.506 us; speedup vs baseline: 1.9860x; 1.0104x over previous
//
#include <hip/hip_runtime.h>
#include <stdint.h>

typedef unsigned short u16;
typedef __attribute__((ext_vector_type(8))) __bf16 bf16x8;
typedef __attribute__((ext_vector_type(4))) __bf16 bf16x4;
typedef __attribute__((ext_vector_type(4))) float f32x4;
typedef __attribute__((ext_vector_type(8))) u16 u16x8;
typedef __attribute__((ext_vector_type(4))) short s16x4;
typedef __attribute__((ext_vector_type(2))) unsigned int u32x2;

#define B_SZ 2
#define T_SZ 2048
#define C_SZ 2048
#define H_SZ 16
#define D_SZ 128
#define NQKV 2304   // C + D + D (q | k | v)
#define ATT_SCALE 0.08838834764831845f
#define LOG2E_SCALE 0.12751744f     // ATT_SCALE * log2(e)
#define DEFER_THR2 11.5415603f      // 8 * log2(e): defer threshold in log2 domain

typedef __attribute__((address_space(1))) void* as1_void_p;
typedef __attribute__((address_space(3))) void* as3_void_p;

__device__ __forceinline__ u16 f2b(float f) {
  union { float f; uint32_t u; } c; c.f = f;
  return (u16)((c.u + 0x7FFFu + ((c.u >> 16) & 1u)) >> 16);
}

__device__ __forceinline__ void gload_lds16(const u16* g, u16* l) {
  __builtin_amdgcn_global_load_lds((as1_void_p)g, (as3_void_p)l, 16, 0, 0);
}

// K=16 bf16 MFMA (intrinsic: hazard recognizer must see it; round-6 verified)
__device__ __forceinline__ f32x4 mfma16(s16x4 a, s16x4 b, f32x4 c) {
#if __has_builtin(__builtin_amdgcn_mfma_f32_16x16x16bf16_1k)
  return __builtin_amdgcn_mfma_f32_16x16x16bf16_1k(a, b, c, 0, 0, 0);
#elif __has_builtin(__builtin_amdgcn_mfma_f32_16x16x16_bf16)
  return __builtin_amdgcn_mfma_f32_16x16x16_bf16(
      __builtin_bit_cast(bf16x4, a), __builtin_bit_cast(bf16x4, b), c, 0, 0, 0);
#else
  u32x2 ua = __builtin_bit_cast(u32x2, a);
  u32x2 ub = __builtin_bit_cast(u32x2, b);
  asm("s_nop 1\n\tv_mfma_f32_16x16x16_bf16 %0, %1, %2, %0\n\ts_nop 7"
      : "+v"(c) : "v"(ua), "v"(ub));
  return c;
#endif
}

// ---------------- merged prep: all casts + bias concat, ONE launch ----------------
__device__ __forceinline__ void cast4(const float* __restrict__ in,
                                      u16* __restrict__ out, int lb, int tid) {
  int idx = lb * 1024 + tid * 4;
  float4 f = *(const float4*)&in[idx];
  ushort4 o4;
  o4.x = f2b(f.x); o4.y = f2b(f.y); o4.z = f2b(f.z); o4.w = f2b(f.w);
  *(ushort4*)&out[idx] = o4;
}

__global__ __launch_bounds__(256) void prep(const float* __restrict__ x,
                                            const float* __restrict__ Wq,
                                            const float* __restrict__ Wk,
                                            const float* __restrict__ Wv,
                                            const float* __restrict__ Wo,
                                            const float* __restrict__ bq,
                                            const float* __restrict__ bk,
                                            const float* __restrict__ bv,
                                            u16* __restrict__ xb,
                                            u16* __restrict__ wqkv,
                                            u16* __restrict__ wob,
                                            float* __restrict__ bqkv) {
  const int bid = blockIdx.x, tid = threadIdx.x;
  if (bid < 8192)       cast4(x,  xb,              bid,         tid);   // 8388608
  else if (bid < 12288) cast4(Wq, wqkv,            bid - 8192,  tid);   // 4194304
  else if (bid < 12544) cast4(Wk, wqkv + 4194304,  bid - 12288, tid);   // 262144
  else if (bid < 12800) cast4(Wv, wqkv + 4456448,  bid - 12544, tid);   // 262144
  else if (bid < 16896) cast4(Wo, wob,             bid - 12800, tid);   // 4194304
  else {
    int e = (bid - 16896) * 1024 + tid * 4;
#pragma unroll
    for (int j = 0; j < 4; j++) {
      int i = e + j;
      if (i < NQKV)
        bqkv[i] = i < C_SZ ? bq[i] : (i < C_SZ + D_SZ ? bk[i - C_SZ] : bv[i - C_SZ - D_SZ]);
    }
  }
}

// ---------------- GEMM: C[M,N] = A[M,K] @ Bm[N,K]^T + bias ----------------
// 128xBN tile, BK=32, 4 waves (2x2), 2-phase pipeline + bijective XCD swizzle.
// BN=96 for the QKV GEMM (768 wg = 3.0/CU); BN=128 for the output GEMM.
// WVT: fuse the V-transpose into the epilogue -- for cols >= C+D the lane's
// 4-row fragment is 4 consecutive t at fixed d -> one contiguous 8B store to
// vT[b][d][t] (predicate is fragment-uniform since 2176 % 16 == 0; batch is
// constant within a 128-row tile). Replaces the separate transpose_v kernel.
template <typename OutT, int BN, bool WVT>
__global__ __launch_bounds__(256) void gemm_bt(const u16* __restrict__ A,
                                               const u16* __restrict__ Bm,
                                               const float* __restrict__ bias,
                                               OutT* __restrict__ C,
                                               u16* __restrict__ vTo,
                                               int K, int ldc) {
  constexpr int WN = BN / 2;    // per-wave n extent
  constexpr int NF = BN / 32;   // 16-wide n frags per wave
  __shared__ u16 lsA[2][128 * 32];
  __shared__ u16 lsB[2][BN * 32];
  const int tid = threadIdx.x;
  const int lane = tid & 63;
  const int wave = tid >> 6;
  const int wr = wave >> 1, wc = wave & 1;
  const int l16 = lane & 15, lq = lane >> 4;
  const int nwg = gridDim.x * gridDim.y;
  int wg = blockIdx.y * gridDim.x + blockIdx.x;
  wg = (wg & 7) * (nwg >> 3) + (wg >> 3);          // bijective (nwg % 8 == 0)
  const int brow = (wg / gridDim.x) * 128;
  const int bcol = (wg % gridDim.x) * BN;

  f32x4 acc[4][NF] = {};

  // chunk c (16B, 8 elems): source row = c>>2, col = (c&3)*8; dest linear c*8.
  auto STAGE = [&](int k0, int bs) {
#pragma unroll
    for (int i = 0; i < 2; i++) {            // A: 512 chunks
      const int cA = i * 256 + wave * 64 + lane;
      const int r = cA >> 2, cc = cA & 3;
      gload_lds16(A + (size_t)(brow + r) * K + k0 + cc * 8,
                  &lsA[bs][(i * 256 + wave * 64) * 8]);
    }
    constexpr int NCB = BN * 4;              // B chunks (512 or 384)
#pragma unroll
    for (int i = 0; i < NCB / 256; i++) {
      const int cB = i * 256 + wave * 64 + lane;
      const int r = cB >> 2, cc = cB & 3;
      gload_lds16(Bm + (size_t)(bcol + r) * K + k0 + cc * 8,
                  &lsB[bs][(i * 256 + wave * 64) * 8]);
    }
    if constexpr (NCB % 256 != 0) {          // remainder: wave-uniform subset
      if (wave < (NCB % 256) / 64) {
        const int cB = (NCB / 256) * 256 + wave * 64 + lane;
        const int r = cB >> 2, cc = cB & 3;
        gload_lds16(Bm + (size_t)(bcol + r) * K + k0 + cc * 8,
                    &lsB[bs][((NCB / 256) * 256 + wave * 64) * 8]);
      }
    }
  };

  STAGE(0, 0);
  __syncthreads();
  int cur = 0;
  for (int k0 = 0; k0 < K; k0 += 32) {
    if (k0 + 32 < K) STAGE(k0 + 32, cur ^ 1);

    bf16x8 af[4], bfr[NF];
#pragma unroll
    for (int mi = 0; mi < 4; mi++)
      af[mi] = *(const bf16x8*)&lsA[cur][(wr * 64 + mi * 16 + l16) * 32 + lq * 8];
#pragma unroll
    for (int ni = 0; ni < NF; ni++)
      bfr[ni] = *(const bf16x8*)&lsB[cur][(wc * WN + ni * 16 + l16) * 32 + lq * 8];
#pragma unroll
    for (int mi = 0; mi < 4; mi++)
#pragma unroll
      for (int ni = 0; ni < NF; ni++)
        acc[mi][ni] = __builtin_amdgcn_mfma_f32_16x16x32_bf16(af[mi], bfr[ni], acc[mi][ni], 0, 0, 0);

    __syncthreads();
    cur ^= 1;
  }

#pragma unroll
  for (int mi = 0; mi < 4; mi++)
#pragma unroll
    for (int ni = 0; ni < NF; ni++) {
      const int col = bcol + wc * WN + ni * 16 + l16;
      const float bb = bias ? bias[col] : 0.0f;
      u16 w4[4];
#pragma unroll
      for (int r = 0; r < 4; r++) {
        const int row = brow + wr * 64 + mi * 16 + lq * 4 + r;
        const float v = acc[mi][ni][r] + bb;
        if constexpr (sizeof(OutT) == 2) {
          const u16 hv = f2b(v);
          ((u16*)C)[(size_t)row * ldc + col] = hv;
          w4[r] = hv;
        } else {
          ((float*)C)[(size_t)row * ldc + col] = v;
        }
      }
      if constexpr (WVT) {
        if (col >= C_SZ + D_SZ) {           // V columns: fused transpose store
          const int d = col - (C_SZ + D_SZ);
          const int row0 = brow + wr * 64 + mi * 16 + lq * 4;
          const int bb_ = row0 >> 11, t0 = row0 & (T_SZ - 1);
          ushort4 sv;
          sv.x = w4[0]; sv.y = w4[1]; sv.z = w4[2]; sv.w = w4[3];
          *(ushort4*)&vTo[((size_t)(bb_ * D_SZ + d)) * T_SZ + t0] = sv;
        }
      }
    }
}

// ---------------- per-wave QK^T (swapped operands) ----------------
// lk: [64 kv][128 d] bf16, 16B chunks XOR-swizzled by (row&7)
__device__ __forceinline__ void qk_part(const u16* lk, const bf16x8 (&aq)[4],
                                        f32x4 (&s)[4], int l16, int lq) {
#pragma unroll
  for (int kk = 0; kk < 4; kk++) {
#pragma unroll
    for (int nb = 0; nb < 4; nb++) {
      const int row = nb * 16 + l16;
      const bf16x8 kf = *(const bf16x8*)&lk[row * 128 + (((kk * 4 + lq) ^ (row & 7)) << 3)];
      s[nb] = __builtin_amdgcn_mfma_f32_16x16x32_bf16(kf, aq[kk], s[nb], 0, 0, 0);
    }
  }
}

// ---------------- per-wave softmax + PV ----------------
// Q is PRE-SCALED by ATT_SCALE*log2(e) at block init: p = exp2(s - m) directly.
// S^T regs: lane has q=l16 fixed, kv = nb*16+lq*4+rr. PV K=16 MFMA B-operand
// (col=l16, k=lq*4+e) == the S^T fragment -> zero cross-lane P movement.
// lv: [128 d][64 t] bf16, 16B chunks XOR-swizzled by (row&7). Round-21 lesson:
// LDS staging converts scattered per-MFMA V gathers into one coalesced
// prefetch -- direct-global V was 3x slower; keep the staging.
template <bool DIAG>
__device__ __forceinline__ void sm_pv(const u16* lv, f32x4 (&s)[4], f32x4 (&o)[8],
                                      float& lp, float& m, int q_rel, int l16, int lq) {
  if (DIAG) {
#pragma unroll
    for (int nb = 0; nb < 4; nb++)
#pragma unroll
      for (int rr = 0; rr < 4; rr++)
        if (nb * 16 + lq * 4 + rr > q_rel) s[nb][rr] -= 1e9f;  // additive causal mask
  }
  // balanced lane-local max tree (no cross-lane ops on the common path)
  float m0 = fmaxf(fmaxf(s[0][0], s[0][1]), fmaxf(s[0][2], s[0][3]));
  float m1 = fmaxf(fmaxf(s[1][0], s[1][1]), fmaxf(s[1][2], s[1][3]));
  float m2 = fmaxf(fmaxf(s[2][0], s[2][1]), fmaxf(s[2][2], s[2][3]));
  float m3 = fmaxf(fmaxf(s[3][0], s[3][1]), fmaxf(s[3][2], s[3][3]));
  float mx = fmaxf(fmaxf(m0, m1), fmaxf(m2, m3));
  if (__any(mx > m + DEFER_THR2)) {  // defer-max (T13); fires iff row-max fires
    float rmx = fmaxf(mx, __shfl_xor(mx, 16, 64));   // row max (rare path)
    rmx = fmaxf(rmx, __shfl_xor(rmx, 32, 64));
    const float mnew = fmaxf(m, rmx);                // row-uniform
    const float alpha = exp2f(m - mnew);
    m = mnew;
    lp *= alpha;
#pragma unroll
    for (int nd = 0; nd < 8; nd++)
#pragma unroll
      for (int e = 0; e < 4; e++) o[nd][e] *= alpha;
  }
#pragma unroll
  for (int nb = 0; nb < 4; nb++) {
    bf16x4 pbv;
#pragma unroll
    for (int e = 0; e < 4; e++) {
      const float p = exp2f(s[nb][e] - m);
      lp += p;
      pbv[e] = (__bf16)p;          // native cvt (compiler may pack pairs)
    }
    const s16x4 pb = __builtin_bit_cast(s16x4, pbv);
    __builtin_amdgcn_s_setprio(1);   // T5
#pragma unroll
    for (int nd = 0; nd < 8; nd++) {
      const int row = nd * 16 + l16;
      const s16x4 av = *(const s16x4*)&lv[row * 64 +
          ((((nb << 1) | (lq >> 1)) ^ (row & 7)) << 3) + ((lq & 1) << 2)];
      o[nd] = mfma16(av, pb, o[nd]);
    }
    __builtin_amdgcn_s_setprio(0);
  }
}

// ---------------- flash attention, causal, MQA ----------------
// grid (16, H, B), 512 threads = 8 waves, ALL on ONE 128-row q-tile
// (wave wv owns rows qt*128 + wv*16). nkt = 2*qt+2; b-complementary qt mapping
// keeps co-resident nkt sums constant. K+V double-buffered (64KB, 2 blocks/CU),
// one vmcnt(0)+barrier per iteration (measured plateau ~91.5us across all
// structural/micro variants -- decomposition-bound at 16 waves/CU).
__global__ __launch_bounds__(512, 4) void attn_fwd(const u16* __restrict__ qkv,
                                                   const u16* __restrict__ vT,
                                                   u16* __restrict__ out) {
  __shared__ u16 lsK[2][64 * 128];
  __shared__ u16 lsV[2][128 * 64];
  const int tid = threadIdx.x;
  const int wv = tid >> 6, lane = tid & 63;
  const int l16 = lane & 15, lq = lane >> 4;
  const int h = blockIdx.y;
  const int b = blockIdx.z;
  // 128-row q-tile index in [0,16); heavy-first for b=0, complementary for b=1
  const int qt = (b == 0) ? (15 - blockIdx.x) : blockIdx.x;
  const int bT = b * T_SZ;
  const int wq0 = qt * 128 + wv * 16;    // this wave's first q row

  bf16x8 aq[4];
  {
    const size_t qrow = (size_t)(bT + wq0 + l16) * NQKV + h * D_SZ;
#pragma unroll
    for (int kk = 0; kk < 4; kk++) {
      aq[kk] = *(const bf16x8*)&qkv[qrow + kk * 32 + lq * 8];
      // pre-scale Q by ATT_SCALE*log2(e): softmax then needs no per-value mul
#pragma unroll
      for (int e = 0; e < 8; e++)
        aq[kk][e] = (__bf16)((float)aq[kk][e] * LOG2E_SCALE);
    }
  }

  f32x4 o[8] = {};
  float lp = 0.f, m = -INFINITY;

  // staging pointers: 512 threads, 2 x 16B loads each for K and for V.
  // linear dest = idx*16B (idx = i*512 + tid); source pre-swizzled by row.
  const u16 *kp0, *kp1, *vp0, *vp1;
  {
    const int kr0 = tid >> 4,         kc0 = tid & 15;
    const int kr1 = (512 + tid) >> 4, kc1 = tid & 15;
    kp0 = qkv + (size_t)(bT + kr0) * NQKV + C_SZ + (size_t)((kc0 ^ (kr0 & 7)) * 8);
    kp1 = qkv + (size_t)(bT + kr1) * NQKV + C_SZ + (size_t)((kc1 ^ (kr1 & 7)) * 8);
    const int vr0 = tid >> 3,         vc0 = tid & 7;
    const int vr1 = (512 + tid) >> 3, vc1 = tid & 7;
    vp0 = vT + (size_t)(b * D_SZ + vr0) * T_SZ + (vc0 ^ (vr0 & 7)) * 8;
    vp1 = vT + (size_t)(b * D_SZ + vr1) * T_SZ + (vc1 ^ (vr1 & 7)) * 8;
  }
  const int kd0 = wv * 512, kd1 = (8 + wv) * 512;

  auto STAGE_K = [&](int kt, int bf) {
    const size_t off = (size_t)kt * (64 * NQKV);
    gload_lds16(kp0 + off, &lsK[bf][kd0]);
    gload_lds16(kp1 + off, &lsK[bf][kd1]);
  };
  auto STAGE_V = [&](int kt, int bf) {
    const int off = kt * 64;
    gload_lds16(vp0 + off, &lsV[bf][kd0]);
    gload_lds16(vp1 + off, &lsV[bf][kd1]);
  };

  const int nkt = 2 * qt + 2;
  STAGE_K(0, 0);
  STAGE_V(0, 0);
  __syncthreads();   // prologue: full drain before first consume
  int cur = 0;
  for (int kt = 0; kt < nkt; kt++) {
    if (kt + 1 < nkt) {                 // prefetch both tiles into cur^1;
      STAGE_K(kt + 1, cur ^ 1);         // flies under the WHOLE iteration
      STAGE_V(kt + 1, cur ^ 1);
    }
    const int kv0 = kt << 6;
    if (kv0 <= wq0 + 15) {              // this wave still has unmasked work
      f32x4 s[4] = {};
      __builtin_amdgcn_s_setprio(1);    // T5: favor QK MFMA cluster
      qk_part(lsK[cur], aq, s, l16, lq);
      __builtin_amdgcn_s_setprio(0);
      if (kv0 + 63 <= wq0)
        sm_pv<false>(lsV[cur], s, o, lp, m, 0, l16, lq);
      else
        sm_pv<true>(lsV[cur], s, o, lp, m, wq0 + l16 - kv0, l16, lq);
    }
    // single sync point: drain prefetch (covered by compute above), publish
    // LDS writes, and protect [cur] from next iteration's staging.
    asm volatile("s_waitcnt vmcnt(0)" ::: "memory");
    __builtin_amdgcn_sched_barrier(0);
    __builtin_amdgcn_s_barrier();
    cur ^= 1;
  }

  // epilogue: reduce deferred row sum, normalize, store (O^T: 8B contiguous)
  lp += __shfl_xor(lp, 16, 64);
  lp += __shfl_xor(lp, 32, 64);
  const float r = __builtin_amdgcn_rcpf(lp);
  const size_t rowb = (size_t)(bT + wq0 + l16) * C_SZ + h * D_SZ;
#pragma unroll
  for (int nd = 0; nd < 8; nd++) {
    ushort4 sv;
    sv.x = f2b(o[nd][0] * r); sv.y = f2b(o[nd][1] * r);
    sv.z = f2b(o[nd][2] * r); sv.w = f2b(o[nd][3] * r);
    *(ushort4*)&out[rowb + nd * 16 + lq * 4] = sv;
  }
}

extern "C" void kernel_launch(void* const* d_in, const int* in_sizes, int n_in,
                              void* d_out, int out_size, void* d_ws, size_t ws_size,
                              hipStream_t stream) {
  const float* x  = (const float*)d_in[0];
  // d_in[1] = attn_mask: causal, hardcoded in attn_fwd
  const float* Wq = (const float*)d_in[2];
  const float* bq = (const float*)d_in[3];
  const float* Wk = (const float*)d_in[4];
  const float* bk = (const float*)d_in[5];
  const float* Wv = (const float*)d_in[6];
  const float* bv = (const float*)d_in[7];
  const float* Wo = (const float*)d_in[8];
  const float* bo = (const float*)d_in[9];
  float* out = (float*)d_out;

  // workspace layout (bytes), all 256-aligned
  char* ws = (char*)d_ws;
  if (ws_size < 71312384) return;  // need ~68 MB
  u16* xb     = (u16*)(ws + 0);          // 4096x2048 bf16
  u16* wqkv   = (u16*)(ws + 16777216);   // 2304x2048 bf16 (Wq|Wk|Wv rows)
  u16* wob    = (u16*)(ws + 26214400);   // 2048x2048 bf16
  u16* qkv    = (u16*)(ws + 34603008);   // 4096x2304 bf16
  u16* vT     = (u16*)(ws + 53477376);   // 2x128x2048 bf16
  u16* ao     = (u16*)(ws + 54525952);   // 4096x2048 bf16
  float* bqkv = (float*)(ws + 71303168); // 2304 f32

  prep<<<16899, 256, 0, stream>>>(x, Wq, Wk, Wv, Wo, bq, bk, bv, xb, wqkv, wob, bqkv);

  // qkv = xb @ wqkv^T + bias  [4096, 2304]  (128x96: 768 wg = 3.0/CU);
  // V-transpose fused into the epilogue (writes vT directly).
  gemm_bt<u16, 96, true><<<dim3(24, 32), 256, 0, stream>>>(
      xb, wqkv, bqkv, qkv, vT, 2048, NQKV);
  attn_fwd<<<dim3(16, 16, 2), 512, 0, stream>>>(qkv, vT, ao);
  // out = ao @ wob^T + bo     [4096, 2048] fp32  (128x128: 512 wg = 2.0/CU)
  gemm_bt<float, 128, false><<<dim3(16, 32), 256, 0, stream>>>(
      ao, wob, bo, out, nullptr, 2048, 2048);
}